// Round 1
// baseline (114.954 us; speedup 1.0000x reference)
//
#include <hip/hip_runtime.h>
#include <math.h>

#define CLS_NUM 16
#define NB 16
#define NH 160
#define NW 160
#define NCH 22          // 6 + CLS_NUM
#define NT 2048
#define TPB 256
#define EPS_F 1e-7f

// ---------------- ws layout (floats) ----------------
// raw    : 6*NT   per-target params, unsorted (cos,sin,x3,x4,y3,y4 as 6 planes)
// sorted : 6*NT   same, sorted by segment
// segArr : NT ints
// counts : 256 ints
// offs   : 256 ints
// cursor : 256 ints
// accum  : 64 floats (per class: cobj, cnoobj, aobj, anoobj)

__global__ void prep_kernel(const float* __restrict__ targets,
                            float* __restrict__ raw,
                            int* __restrict__ segArr,
                            int* __restrict__ counts) {
    int n = blockIdx.x * blockDim.x + threadIdx.x;
    if (n >= NT) return;
    const float* t = targets + n * 7;
    int b = (int)t[0];
    int c = (int)t[1];
    float cx = t[2] * 0.125f;   // /SCALE, exact
    float cy = t[3] * 0.125f;
    float w  = t[4] * 0.125f;
    float h  = t[5] * 0.125f;
    float ang = t[6];
    float cs = cosf(ang), sn = sinf(ang);
    float xr =  cx * cs + cy * sn;
    float yr = -cx * sn + cy * cs;
    raw[0 * NT + n] = cs;
    raw[1 * NT + n] = sn;
    raw[2 * NT + n] = xr - h * 0.5f;   // x3
    raw[3 * NT + n] = xr + h * 0.5f;   // x4
    raw[4 * NT + n] = yr - w * 0.5f;   // y3
    raw[5 * NT + n] = yr + w * 0.5f;   // y4
    int seg = c * NB + b;
    segArr[n] = seg;
    atomicAdd(&counts[seg], 1);
}

__global__ void scan_kernel(const int* __restrict__ counts,
                            int* __restrict__ offs,
                            int* __restrict__ cursor) {
    __shared__ int tmp[256];
    int t = threadIdx.x;
    int myc = counts[t];
    tmp[t] = myc;
    __syncthreads();
    for (int off = 1; off < 256; off <<= 1) {
        int v = (t >= off) ? tmp[t - off] : 0;
        __syncthreads();
        tmp[t] += v;
        __syncthreads();
    }
    int excl = tmp[t] - myc;
    offs[t] = excl;
    cursor[t] = excl;
}

__global__ void scatter_kernel(const float* __restrict__ raw,
                               const int* __restrict__ segArr,
                               int* __restrict__ cursor,
                               float* __restrict__ sorted) {
    int n = blockIdx.x * blockDim.x + threadIdx.x;
    if (n >= NT) return;
    int seg = segArr[n];
    int pos = atomicAdd(&cursor[seg], 1);
    #pragma unroll
    for (int a = 0; a < 6; a++) sorted[a * NT + pos] = raw[a * NT + n];
}

// grid: (256 pairs, 10 row-tiles), block 256. pair == seg == c*16+b.
__global__ void mask_loss_kernel(const float* __restrict__ predict,
                                 const float* __restrict__ sorted,
                                 const int* __restrict__ offs,
                                 const int* __restrict__ counts,
                                 float* __restrict__ accum) {
    int pair = blockIdx.x;
    int c = pair >> 4;
    int b = pair & 15;
    int rowbase = blockIdx.y * 16;
    int tid = threadIdx.x;
    int start = offs[pair];
    int cnt = counts[pair];

    __shared__ float scs[TPB], ssn[TPB], sx3[TPB], sx4[TPB], sy3[TPB], sy4[TPB];

    unsigned int objb = 0, wideb = 0;
    for (int base = 0; base < cnt; base += TPB) {
        int m = min(TPB, cnt - base);
        if (tid < m) {
            int p = start + base + tid;
            scs[tid] = sorted[0 * NT + p];
            ssn[tid] = sorted[1 * NT + p];
            sx3[tid] = sorted[2 * NT + p];
            sx4[tid] = sorted[3 * NT + p];
            sy3[tid] = sorted[4 * NT + p];
            sy4[tid] = sorted[5 * NT + p];
        }
        __syncthreads();
        #pragma unroll
        for (int k = 0; k < 10; k++) {
            int local = tid + k * TPB;            // 0..2559
            int i = rowbase + local / NW;
            int j = local % NW;
            float gx = j + 0.5f;
            float gy = i + 0.5f;
            bool obj = false, wide = false;
            for (int t = 0; t < m; t++) {
                float cs = scs[t], sn = ssn[t];
                float vx = cs * gx + sn * gy;
                float vy = cs * gy - sn * gx;     // == -sn*gx + cs*gy
                float x3 = sx3[t], x4 = sx4[t], y3 = sy3[t], y4 = sy4[t];
                bool o_ = (x3 <= vx) & (vx <= x4) & (y3 <= vy) & (vy <= y4);
                bool w_ = (x3 - 0.5f <= vx) & (vx <= x4 + 0.5f) &
                          (y3 - 0.5f <= vy) & (vy <= y4 + 0.5f);
                obj = obj | o_;
                wide = wide | w_;
            }
            objb  |= (unsigned int)obj  << k;
            wideb |= (unsigned int)wide << k;
        }
        __syncthreads();
    }

    // confidence loss over this (c,b) channel, this row-tile
    float aobj = 0.f, anoobj = 0.f, cobj = 0.f, cnoobj = 0.f;
    const float* cp = predict + ((size_t)(b * NCH + 6 + c) * NH) * NW;
    #pragma unroll
    for (int k = 0; k < 10; k++) {
        int local = tid + k * TPB;
        int i = rowbase + local / NW;
        int j = local % NW;
        float pv = cp[i * NW + j];
        float s = 1.0f / (1.0f + expf(-pv));
        float sc = fminf(fmaxf(s, EPS_F), 1.0f - EPS_F);
        if ((objb >> k) & 1u) { aobj -= logf(sc); cobj += 1.0f; }
        if (!((wideb >> k) & 1u)) { anoobj -= logf(1.0f - sc); cnoobj += 1.0f; }
    }

    // block reduce (reuse LDS arrays — all prior reads fenced by last __syncthreads)
    scs[tid] = aobj; ssn[tid] = anoobj; sx3[tid] = cobj; sx4[tid] = cnoobj;
    __syncthreads();
    for (int s2 = TPB / 2; s2 > 0; s2 >>= 1) {
        if (tid < s2) {
            scs[tid] += scs[tid + s2];
            ssn[tid] += ssn[tid + s2];
            sx3[tid] += sx3[tid + s2];
            sx4[tid] += sx4[tid + s2];
        }
        __syncthreads();
    }
    if (tid == 0) {
        atomicAdd(&accum[c * 4 + 0], sx3[0]);   // n_obj
        atomicAdd(&accum[c * 4 + 1], sx4[0]);   // n_noobj
        atomicAdd(&accum[c * 4 + 2], scs[0]);   // loss_obj sum
        atomicAdd(&accum[c * 4 + 3], ssn[0]);   // loss_noobj sum
    }
}

__global__ void boxes_kernel(const float* __restrict__ predict,
                             float* __restrict__ out) {
    int idx = blockIdx.x * TPB + threadIdx.x;
    if (idx >= NB * NH * NW) return;
    int b = idx / (NH * NW);
    int cell = idx % (NH * NW);
    int i = cell / NW;
    int j = cell % NW;
    const int CS = NH * NW;
    const float* pb = predict + ((size_t)(b * NCH) * NH + i) * NW + j;

    float p0 = pb[0 * CS], p1 = pb[1 * CS], p2 = pb[2 * CS];
    float p3 = pb[3 * CS], p4 = pb[4 * CS], p5 = pb[5 * CS];

    float x = 1.0f / (1.0f + expf(-p0)) * 5.0f - 2.0f;
    float y = 1.0f / (1.0f + expf(-p1)) * 5.0f - 2.0f;
    float p = 1.0f / (1.0f + expf(-p4)) * 2.0f - 1.0f;
    float q = 1.0f / (1.0f + expf(-p5)) * 2.0f - 1.0f;

    float best = -1.0f;
    int bi = 0;
    #pragma unroll
    for (int cc = 0; cc < CLS_NUM; cc++) {
        float s = 1.0f / (1.0f + expf(-pb[(6 + cc) * CS]));
        if (s > best) { best = s; bi = cc; }   // strict > keeps first index (argmax)
    }

    float t = sqrtf((1.0f + p) * 0.5f + 1e-16f);
    float bang = atan2f(q / (2.0f * t + 1e-16f), t);

    float* o = out + 1 + (size_t)idx * 7;
    o[0] = best;
    o[1] = (float)bi;
    o[2] = ((float)j + x) * 8.0f;
    o[3] = ((float)i + y) * 8.0f;
    o[4] = expf(p2) * 8.0f;
    o[5] = expf(p3) * 8.0f;
    o[6] = bang;
}

__global__ void loss_kernel(const float* __restrict__ accum,
                            float* __restrict__ out) {
    if (threadIdx.x == 0 && blockIdx.x == 0) {
        float L = 0.f;
        for (int c = 0; c < CLS_NUM; c++) {
            float cobj = accum[c * 4 + 0];
            float cno  = accum[c * 4 + 1];
            float ao   = accum[c * 4 + 2];
            float an   = accum[c * 4 + 3];
            if (cobj > 0.0f) {
                L += ao / fmaxf(cobj, 1.0f) + an / fmaxf(cno, 1.0f);
            }
        }
        out[0] = L;
    }
}

extern "C" void kernel_launch(void* const* d_in, const int* in_sizes, int n_in,
                              void* d_out, int out_size, void* d_ws, size_t ws_size,
                              hipStream_t stream) {
    const float* predict = (const float*)d_in[0];
    const float* targets = (const float*)d_in[1];
    float* out = (float*)d_out;

    float* W      = (float*)d_ws;
    float* raw    = W;                    // 6*NT
    float* sorted = W + 6 * NT;           // 6*NT
    int*   segArr = (int*)(W + 12 * NT);  // NT
    int*   counts = segArr + NT;          // 256
    int*   offs   = counts + 256;         // 256
    int*   cursor = offs + 256;           // 256
    float* accum  = (float*)(cursor + 256); // 64

    // zero counts/offs/cursor/accum each call (deterministic)
    hipMemsetAsync(counts, 0, (3 * 256 + 64) * sizeof(int), stream);

    prep_kernel<<<(NT + TPB - 1) / TPB, TPB, 0, stream>>>(targets, raw, segArr, counts);
    scan_kernel<<<1, 256, 0, stream>>>(counts, offs, cursor);
    scatter_kernel<<<(NT + TPB - 1) / TPB, TPB, 0, stream>>>(raw, segArr, cursor, sorted);
    mask_loss_kernel<<<dim3(256, 10), TPB, 0, stream>>>(predict, sorted, offs, counts, accum);
    loss_kernel<<<1, 64, 0, stream>>>(accum, out);
    boxes_kernel<<<(NB * NH * NW + TPB - 1) / TPB, TPB, 0, stream>>>(predict, out);
}

// Round 2
// 57.494 us; speedup vs baseline: 1.9994x; 1.9994x over previous
//
#include <hip/hip_runtime.h>
#include <math.h>

#define CLS_NUM 16
#define NB 16
#define NH 160
#define NW 160
#define NCH 22          // 6 + CLS_NUM
#define NT 2048
#define TPB 256
#define EPS_F 1e-7f

// ---------------- ws layout ----------------
// sorted : NT*6 floats (AoS: cs,sn,x3,x4,y3,y4 per target, sorted by seg)
// offs   : 256 ints
// counts : 256 ints
// accum  : 64 floats (per class: aobj, anoobj, cobj, cnoobj)

// Single block: prep (cos/sin + box params), counting sort by seg=c*16+b.
__global__ __launch_bounds__(256) void prep_sort_kernel(
        const float* __restrict__ targets,
        float* __restrict__ sorted,
        int* __restrict__ offs,
        int* __restrict__ counts) {
    __shared__ int cnt_s[256];
    __shared__ int scan_s[256];
    __shared__ int cur_s[256];
    int tid = threadIdx.x;
    cnt_s[tid] = 0;
    __syncthreads();

    float prm[8][6];
    int   segs[8];
    #pragma unroll
    for (int it = 0; it < 8; it++) {
        int n = it * 256 + tid;
        const float* t = targets + n * 7;
        float b = t[0], c = t[1];
        float cx = t[2] * 0.125f, cy = t[3] * 0.125f;
        float w  = t[4] * 0.125f, h  = t[5] * 0.125f;
        float ang = t[6];
        float cs = cosf(ang), sn = sinf(ang);
        float xr =  cx * cs + cy * sn;
        float yr = -cx * sn + cy * cs;
        prm[it][0] = cs; prm[it][1] = sn;
        prm[it][2] = xr - h * 0.5f;  prm[it][3] = xr + h * 0.5f;
        prm[it][4] = yr - w * 0.5f;  prm[it][5] = yr + w * 0.5f;
        int seg = (int)c * NB + (int)b;
        segs[it] = seg;
        atomicAdd(&cnt_s[seg], 1);
    }
    __syncthreads();
    // inclusive scan over 256 counts
    int myc = cnt_s[tid];
    scan_s[tid] = myc;
    __syncthreads();
    for (int off = 1; off < 256; off <<= 1) {
        int v = (tid >= off) ? scan_s[tid - off] : 0;
        __syncthreads();
        scan_s[tid] += v;
        __syncthreads();
    }
    int excl = scan_s[tid] - myc;
    offs[tid]   = excl;
    counts[tid] = myc;
    cur_s[tid]  = excl;
    __syncthreads();
    #pragma unroll
    for (int it = 0; it < 8; it++) {
        int pos = atomicAdd(&cur_s[segs[it]], 1);
        #pragma unroll
        for (int a = 0; a < 6; a++) sorted[pos * 6 + a] = prm[it][a];
    }
}

// grid: (256 pairs, 10 row-tiles of 16 rows), block 256.
__global__ __launch_bounds__(256) void mask_loss_kernel(
        const float* __restrict__ predict,
        const float* __restrict__ sorted,
        const int* __restrict__ offs,
        const int* __restrict__ counts,
        float* __restrict__ accum) {
    int pair = blockIdx.x;
    int c = pair >> 4;
    int b = pair & 15;
    int rb = blockIdx.y * 16;
    int tid = threadIdx.x;
    int start = offs[pair];
    int cnt   = counts[pair];

    __shared__ float tg[256 * 8];   // staged targets, stride 8 floats
    __shared__ float red[16];

    // per-thread cell coordinates for the 10 cells it owns
    float gxk[10], gyk[10];
    #pragma unroll
    for (int k = 0; k < 10; k++) {
        int local = tid + k * 256;            // 0..2559
        int i = rb + local / NW;
        int j = local % NW;
        gxk[k] = (float)j + 0.5f;
        gyk[k] = (float)i + 0.5f;
    }

    unsigned objb = 0, wideb = 0;
    float rbc = (float)rb + 8.0f;             // tile center y
    for (int base = 0; base < cnt; base += 256) {
        int m = min(256, cnt - base);
        for (int e = tid; e < m * 6; e += 256)
            tg[(e / 6) * 8 + (e % 6)] = sorted[(start + base) * 6 + e];
        __syncthreads();
        for (int t = 0; t < m; t++) {
            float cs = tg[t*8+0], sn = tg[t*8+1];
            float x3 = tg[t*8+2], x4 = tg[t*8+3];
            float y3 = tg[t*8+4], y4 = tg[t*8+5];
            // block-uniform tile reject vs wide box:
            // gx in [0.5,159.5] (center 80, half 79.5), gy in [rb+.5, rb+15.5]
            float acs = fabsf(cs), asn = fabsf(sn);
            float ex  = acs * 79.5f + asn * 7.5f;
            float ey  = acs * 7.5f  + asn * 79.5f;
            float vxc = cs * 80.0f + sn * rbc;
            float vyc = cs * rbc   - sn * 80.0f;
            if (vxc + ex < x3 - 0.5f || vxc - ex > x4 + 0.5f ||
                vyc + ey < y3 - 0.5f || vyc - ey > y4 + 0.5f) continue;
            #pragma unroll
            for (int k = 0; k < 10; k++) {
                float vx = cs * gxk[k] + sn * gyk[k];
                float vy = cs * gyk[k] - sn * gxk[k];
                float mn = fminf(fminf(vx - x3, x4 - vx),
                                 fminf(vy - y3, y4 - vy));
                objb  |= (mn >= 0.0f)  ? (1u << k) : 0u;
                wideb |= (mn >= -0.5f) ? (1u << k) : 0u;
            }
        }
        __syncthreads();
    }

    // confidence loss over this (c,b) channel, this row-tile
    const float* cp = predict + ((size_t)(b * NCH + 6 + c) * NH + rb) * NW;
    float aobj = 0.f, ano = 0.f;
    #pragma unroll
    for (int k = 0; k < 10; k++) {
        float pv = cp[tid + k * 256];
        float s  = 1.0f / (1.0f + __expf(-pv));
        float sc = fminf(fmaxf(s, EPS_F), 1.0f - EPS_F);
        float lo = __logf(sc);
        float ln = __logf(1.0f - sc);
        if ((objb >> k) & 1u)     aobj -= lo;
        if (!((wideb >> k) & 1u)) ano  -= ln;
    }
    float cobj = (float)__popc(objb);
    float cno  = (float)__popc(~wideb & 0x3FFu);

    // wave shfl reduce, then cross-wave via LDS, 4 atomics per block
    #pragma unroll
    for (int o = 32; o > 0; o >>= 1) {
        aobj += __shfl_down(aobj, o);
        ano  += __shfl_down(ano, o);
        cobj += __shfl_down(cobj, o);
        cno  += __shfl_down(cno, o);
    }
    int wid = tid >> 6, lane = tid & 63;
    if (lane == 0) {
        red[wid * 4 + 0] = aobj; red[wid * 4 + 1] = ano;
        red[wid * 4 + 2] = cobj; red[wid * 4 + 3] = cno;
    }
    __syncthreads();
    if (tid < 4) {
        float s = red[tid] + red[4 + tid] + red[8 + tid] + red[12 + tid];
        atomicAdd(&accum[c * 4 + tid], s);
    }
}

__global__ __launch_bounds__(256) void boxes_kernel(
        const float* __restrict__ predict,
        const float* __restrict__ accum,
        float* __restrict__ out) {
    int idx = blockIdx.x * TPB + threadIdx.x;
    // fused final loss (accum complete: prior dispatch on same stream)
    if (blockIdx.x == 0 && threadIdx.x == 0) {
        float L = 0.f;
        for (int c = 0; c < CLS_NUM; c++) {
            float ao   = accum[c * 4 + 0];
            float an   = accum[c * 4 + 1];
            float cobj = accum[c * 4 + 2];
            float cno  = accum[c * 4 + 3];
            if (cobj > 0.0f)
                L += ao / fmaxf(cobj, 1.0f) + an / fmaxf(cno, 1.0f);
        }
        out[0] = L;
    }
    if (idx >= NB * NH * NW) return;
    int b = idx / (NH * NW);
    int cell = idx % (NH * NW);
    int i = cell / NW;
    int j = cell % NW;
    const int CS = NH * NW;
    const float* pb = predict + ((size_t)(b * NCH) * NH + i) * NW + j;

    float p0 = pb[0 * CS], p1 = pb[1 * CS], p2 = pb[2 * CS];
    float p3 = pb[3 * CS], p4 = pb[4 * CS], p5 = pb[5 * CS];

    float x = 1.0f / (1.0f + expf(-p0)) * 5.0f - 2.0f;
    float y = 1.0f / (1.0f + expf(-p1)) * 5.0f - 2.0f;
    float p = 1.0f / (1.0f + expf(-p4)) * 2.0f - 1.0f;
    float q = 1.0f / (1.0f + expf(-p5)) * 2.0f - 1.0f;

    float best = -1.0f;
    int bi = 0;
    #pragma unroll
    for (int cc = 0; cc < CLS_NUM; cc++) {
        float s = 1.0f / (1.0f + expf(-pb[(6 + cc) * CS]));
        if (s > best) { best = s; bi = cc; }   // strict > keeps first index
    }

    float t = sqrtf((1.0f + p) * 0.5f + 1e-16f);
    float bang = atan2f(q / (2.0f * t + 1e-16f), t);

    float* o = out + 1 + (size_t)idx * 7;
    o[0] = best;
    o[1] = (float)bi;
    o[2] = ((float)j + x) * 8.0f;
    o[3] = ((float)i + y) * 8.0f;
    o[4] = expf(p2) * 8.0f;
    o[5] = expf(p3) * 8.0f;
    o[6] = bang;
}

extern "C" void kernel_launch(void* const* d_in, const int* in_sizes, int n_in,
                              void* d_out, int out_size, void* d_ws, size_t ws_size,
                              hipStream_t stream) {
    const float* predict = (const float*)d_in[0];
    const float* targets = (const float*)d_in[1];
    float* out = (float*)d_out;

    float* W      = (float*)d_ws;
    float* sorted = W;                       // NT*6 floats
    int*   offs   = (int*)(W + 6 * NT);      // 256
    int*   counts = offs + 256;              // 256
    float* accum  = (float*)(counts + 256);  // 64 floats

    hipMemsetAsync(accum, 0, 64 * sizeof(float), stream);

    prep_sort_kernel<<<1, 256, 0, stream>>>(targets, sorted, offs, counts);
    mask_loss_kernel<<<dim3(256, 10), TPB, 0, stream>>>(predict, sorted, offs, counts, accum);
    boxes_kernel<<<(NB * NH * NW + TPB - 1) / TPB, TPB, 0, stream>>>(predict, accum, out);
}

// Round 3
// 49.537 us; speedup vs baseline: 2.3206x; 1.1606x over previous
//
#include <hip/hip_runtime.h>
#include <math.h>

#define CLS_NUM 16
#define NB 16
#define NH 160
#define NW 160
#define NCH 22          // 6 + CLS_NUM
#define NT 2048
#define TPB 256
#define EPS_F 1e-7f

// ---------------- ws layout ----------------
// sorted : NT*6 floats (AoS: cs,sn,x3,x4,y3,y4 per target, sorted by seg)
// offs   : 256 ints
// counts : 256 ints
// accum  : 64 floats (per class: aobj, anoobj, cobj, cnoobj)

// Single block: prep (cos/sin + box params), counting sort by seg=c*16+b.
// Also zeroes accum (runs before mask_loss in stream order -> no memset needed).
__global__ __launch_bounds__(256) void prep_sort_kernel(
        const float* __restrict__ targets,
        float* __restrict__ sorted,
        int* __restrict__ offs,
        int* __restrict__ counts,
        float* __restrict__ accum) {
    __shared__ int cnt_s[256];
    __shared__ int scan_s[256];
    __shared__ int cur_s[256];
    int tid = threadIdx.x;
    cnt_s[tid] = 0;
    if (tid < 64) accum[tid] = 0.0f;
    __syncthreads();

    float prm[8][6];
    int   segs[8];
    #pragma unroll
    for (int it = 0; it < 8; it++) {
        int n = it * 256 + tid;
        const float* t = targets + n * 7;
        float b = t[0], c = t[1];
        float cx = t[2] * 0.125f, cy = t[3] * 0.125f;
        float w  = t[4] * 0.125f, h  = t[5] * 0.125f;
        float ang = t[6];
        float cs = cosf(ang), sn = sinf(ang);
        float xr =  cx * cs + cy * sn;
        float yr = -cx * sn + cy * cs;
        prm[it][0] = cs; prm[it][1] = sn;
        prm[it][2] = xr - h * 0.5f;  prm[it][3] = xr + h * 0.5f;
        prm[it][4] = yr - w * 0.5f;  prm[it][5] = yr + w * 0.5f;
        int seg = (int)c * NB + (int)b;
        segs[it] = seg;
        atomicAdd(&cnt_s[seg], 1);
    }
    __syncthreads();
    // inclusive scan over 256 counts
    int myc = cnt_s[tid];
    scan_s[tid] = myc;
    __syncthreads();
    for (int off = 1; off < 256; off <<= 1) {
        int v = (tid >= off) ? scan_s[tid - off] : 0;
        __syncthreads();
        scan_s[tid] += v;
        __syncthreads();
    }
    int excl = scan_s[tid] - myc;
    offs[tid]   = excl;
    counts[tid] = myc;
    cur_s[tid]  = excl;
    __syncthreads();
    #pragma unroll
    for (int it = 0; it < 8; it++) {
        int pos = atomicAdd(&cur_s[segs[it]], 1);
        #pragma unroll
        for (int a = 0; a < 6; a++) sorted[pos * 6 + a] = prm[it][a];
    }
}

// grid: (256 pairs, 10 row-tiles of 16 rows), block 256.
__global__ __launch_bounds__(256) void mask_loss_kernel(
        const float* __restrict__ predict,
        const float* __restrict__ sorted,
        const int* __restrict__ offs,
        const int* __restrict__ counts,
        float* __restrict__ accum) {
    int pair = blockIdx.x;
    int c = pair >> 4;
    int b = pair & 15;
    int rb = blockIdx.y * 16;
    int tid = threadIdx.x;
    int start = offs[pair];
    int cnt   = counts[pair];

    __shared__ float tg[256 * 8];   // staged targets, stride 8 floats
    __shared__ float red[16];

    // per-thread cell coordinates for the 10 cells it owns
    float gxk[10], gyk[10];
    #pragma unroll
    for (int k = 0; k < 10; k++) {
        int local = tid + k * 256;            // 0..2559
        int i = rb + local / NW;
        int j = local % NW;
        gxk[k] = (float)j + 0.5f;
        gyk[k] = (float)i + 0.5f;
    }

    unsigned objb = 0, wideb = 0;
    float rbc = (float)rb + 8.0f;             // tile center y
    for (int base = 0; base < cnt; base += 256) {
        int m = min(256, cnt - base);
        for (int e = tid; e < m * 6; e += 256)
            tg[(e / 6) * 8 + (e % 6)] = sorted[(start + base) * 6 + e];
        __syncthreads();
        for (int t = 0; t < m; t++) {
            float cs = tg[t*8+0], sn = tg[t*8+1];
            float x3 = tg[t*8+2], x4 = tg[t*8+3];
            float y3 = tg[t*8+4], y4 = tg[t*8+5];
            // block-uniform tile reject vs wide box:
            // gx in [0.5,159.5] (center 80, half 79.5), gy in [rb+.5, rb+15.5]
            float acs = fabsf(cs), asn = fabsf(sn);
            float ex  = acs * 79.5f + asn * 7.5f;
            float ey  = acs * 7.5f  + asn * 79.5f;
            float vxc = cs * 80.0f + sn * rbc;
            float vyc = cs * rbc   - sn * 80.0f;
            if (vxc + ex < x3 - 0.5f || vxc - ex > x4 + 0.5f ||
                vyc + ey < y3 - 0.5f || vyc - ey > y4 + 0.5f) continue;
            #pragma unroll
            for (int k = 0; k < 10; k++) {
                float vx = cs * gxk[k] + sn * gyk[k];
                float vy = cs * gyk[k] - sn * gxk[k];
                float mn = fminf(fminf(vx - x3, x4 - vx),
                                 fminf(vy - y3, y4 - vy));
                objb  |= (mn >= 0.0f)  ? (1u << k) : 0u;
                wideb |= (mn >= -0.5f) ? (1u << k) : 0u;
            }
        }
        __syncthreads();
    }

    // confidence loss over this (c,b) channel, this row-tile
    const float* cp = predict + ((size_t)(b * NCH + 6 + c) * NH + rb) * NW;
    float aobj = 0.f, ano = 0.f;
    #pragma unroll
    for (int k = 0; k < 10; k++) {
        float pv = cp[tid + k * 256];
        float s  = 1.0f / (1.0f + __expf(-pv));
        float sc = fminf(fmaxf(s, EPS_F), 1.0f - EPS_F);
        float lo = __logf(sc);
        float ln = __logf(1.0f - sc);
        if ((objb >> k) & 1u)     aobj -= lo;
        if (!((wideb >> k) & 1u)) ano  -= ln;
    }
    float cobj = (float)__popc(objb);
    float cno  = (float)__popc(~wideb & 0x3FFu);

    // wave shfl reduce, then cross-wave via LDS, 4 atomics per block
    #pragma unroll
    for (int o = 32; o > 0; o >>= 1) {
        aobj += __shfl_down(aobj, o);
        ano  += __shfl_down(ano, o);
        cobj += __shfl_down(cobj, o);
        cno  += __shfl_down(cno, o);
    }
    int wid = tid >> 6, lane = tid & 63;
    if (lane == 0) {
        red[wid * 4 + 0] = aobj; red[wid * 4 + 1] = ano;
        red[wid * 4 + 2] = cobj; red[wid * 4 + 3] = cno;
    }
    __syncthreads();
    if (tid < 4) {
        float s = red[tid] + red[4 + tid] + red[8 + tid] + red[12 + tid];
        atomicAdd(&accum[c * 4 + tid], s);
    }
}

__global__ __launch_bounds__(256) void boxes_kernel(
        const float* __restrict__ predict,
        const float* __restrict__ accum,
        float* __restrict__ out) {
    int idx = blockIdx.x * TPB + threadIdx.x;
    // fused final loss (accum complete: prior dispatch on same stream)
    if (blockIdx.x == 0 && threadIdx.x == 0) {
        float L = 0.f;
        for (int c = 0; c < CLS_NUM; c++) {
            float ao   = accum[c * 4 + 0];
            float an   = accum[c * 4 + 1];
            float cobj = accum[c * 4 + 2];
            float cno  = accum[c * 4 + 3];
            if (cobj > 0.0f)
                L += ao / fmaxf(cobj, 1.0f) + an / fmaxf(cno, 1.0f);
        }
        out[0] = L;
    }
    if (idx >= NB * NH * NW) return;
    int b = idx / (NH * NW);
    int cell = idx % (NH * NW);
    int i = cell / NW;
    int j = cell % NW;
    const int CS = NH * NW;
    const float* pb = predict + ((size_t)(b * NCH) * NH + i) * NW + j;

    float p0 = pb[0 * CS], p1 = pb[1 * CS], p2 = pb[2 * CS];
    float p3 = pb[3 * CS], p4 = pb[4 * CS], p5 = pb[5 * CS];

    float x = 1.0f / (1.0f + expf(-p0)) * 5.0f - 2.0f;
    float y = 1.0f / (1.0f + expf(-p1)) * 5.0f - 2.0f;
    float p = 1.0f / (1.0f + expf(-p4)) * 2.0f - 1.0f;
    float q = 1.0f / (1.0f + expf(-p5)) * 2.0f - 1.0f;

    // sigmoid is strictly monotonic: argmax over raw logits == argmax over
    // sigmoid; apply sigmoid once to the winner.
    float bestraw = pb[6 * CS];
    int bi = 0;
    #pragma unroll
    for (int cc = 1; cc < CLS_NUM; cc++) {
        float r = pb[(6 + cc) * CS];
        if (r > bestraw) { bestraw = r; bi = cc; }   // strict > keeps first index
    }
    float best = 1.0f / (1.0f + expf(-bestraw));

    float t = sqrtf((1.0f + p) * 0.5f + 1e-16f);
    float bang = atan2f(q / (2.0f * t + 1e-16f), t);

    float* o = out + 1 + (size_t)idx * 7;
    o[0] = best;
    o[1] = (float)bi;
    o[2] = ((float)j + x) * 8.0f;
    o[3] = ((float)i + y) * 8.0f;
    o[4] = expf(p2) * 8.0f;
    o[5] = expf(p3) * 8.0f;
    o[6] = bang;
}

extern "C" void kernel_launch(void* const* d_in, const int* in_sizes, int n_in,
                              void* d_out, int out_size, void* d_ws, size_t ws_size,
                              hipStream_t stream) {
    const float* predict = (const float*)d_in[0];
    const float* targets = (const float*)d_in[1];
    float* out = (float*)d_out;

    float* W      = (float*)d_ws;
    float* sorted = W;                       // NT*6 floats
    int*   offs   = (int*)(W + 6 * NT);      // 256
    int*   counts = offs + 256;              // 256
    float* accum  = (float*)(counts + 256);  // 64 floats

    prep_sort_kernel<<<1, 256, 0, stream>>>(targets, sorted, offs, counts, accum);
    mask_loss_kernel<<<dim3(256, 10), TPB, 0, stream>>>(predict, sorted, offs, counts, accum);
    boxes_kernel<<<(NB * NH * NW + TPB - 1) / TPB, TPB, 0, stream>>>(predict, accum, out);
}